// Round 6
// baseline (994.542 us; speedup 1.0000x reference)
//
#include <hip/hip_runtime.h>

#define NL 16
#define NT 2048
#define NH 2048
#define NF 512
#define NPAIR 136

typedef short bf16x8 __attribute__((ext_vector_type(8)));
typedef float f32x16 __attribute__((ext_vector_type(16)));
typedef short s16x4 __attribute__((ext_vector_type(4)));

__device__ __forceinline__ short f2bf(float f) {
  union { float f; unsigned u; } x; x.f = f;
  unsigned r = (x.u + 0x7fffu + ((x.u >> 16) & 1u)) >> 16;
  return (short)r;
}

__device__ __forceinline__ int imin(int a, int b) { return a < b ? a : b; }

// ---------------- conversion kernels ----------------

__global__ void k_cvt_f32_bf16(const float* __restrict__ src, short* __restrict__ dst, int n4) {
  int i = blockIdx.x * blockDim.x + threadIdx.x;
  const int stride = gridDim.x * blockDim.x;
  for (; i < n4; i += stride) {
    const float4 v = reinterpret_cast<const float4*>(src)[i];
    s16x4 o;
    o[0] = f2bf(v.x); o[1] = f2bf(v.y); o[2] = f2bf(v.z); o[3] = f2bf(v.w);
    reinterpret_cast<s16x4*>(dst)[i] = o;
  }
}

__global__ void k_cvt_wdec(const float* __restrict__ wdec, short* __restrict__ dst) {
  const int p = blockIdx.y;
  int l = 0;
  while ((l + 1) * (l + 2) / 2 <= p) ++l;
  const int s = p - l * (l + 1) / 2;
  const float* src = wdec + (size_t)(s * NL + l) * (NH * NF);
  short* d = dst + (size_t)p * (NH * NF);
  const int n4 = NH * NF / 4;
  for (int i = blockIdx.x * blockDim.x + threadIdx.x; i < n4; i += gridDim.x * blockDim.x) {
    const float4 v = reinterpret_cast<const float4*>(src)[i];
    s16x4 o;
    o[0] = f2bf(v.x); o[1] = f2bf(v.y); o[2] = f2bf(v.z); o[3] = f2bf(v.w);
    reinterpret_cast<s16x4*>(d)[i] = o;
  }
}

// ---------------- 256x256 GEMM, BK=32, 4-deep LDS ring, 32x32x16 MFMA ----------------
// 8 waves: wr=wave>>2 (2 row-groups of 128), wc=wave&3 (4 col-groups of 64).
// Per-wave output 128x64 = 4x2 tiles of 32x32, acc = f32x16 each (128 VGPR).
// LDS ring: lds[4][2][8192]  (buf u%4: [0]=A 256x32, [1]=B 256x32; 32KB/buf).
// Swizzle (64B rows): element (r, cbyte) at LDS byte (r<<6) | (cbyte ^ ((r&3)<<4)).
//   -> frag reads (32 rows @ 64B stride) spread over 8 16B-slots: 2 lanes/bank, free.
// Per K-tile u (ONE barrier):
//   stage tile u+3 into buf[(u+3)&3]   (4 gload_lds / thread)
//   12 ds_read_b128 (a[2][4], b[2][2]) from buf[u&3]  -- compiler interleaves w/ MFMA
//   16 x mfma_32x32x16 (setprio-wrapped)
//   s_waitcnt vmcnt(8) lgkmcnt(0); s_barrier
// Ledger: WAR: buf[(u+3)&3]=buf[(u-1)&3], last read in tile u-1, drained by that
//   tile's lgkmcnt(0)+barrier. RAW: vmcnt(8) keeps only tiles u+3,u+2 in flight at
//   tile-u end -> buf(u+1) landed; first read of a stage is 3 barriers after issue.
//   Tail: clamp staged source to KT-1 (targets never read again; issue stays uniform).

__device__ __forceinline__ bf16x8 frag32(const short* slot, int row, int kbyte) {
  const int byte = (row << 6) + (kbyte ^ ((row & 3) << 4));
  return *reinterpret_cast<const bf16x8*>(reinterpret_cast<const char*>(slot) + byte);
}

__device__ __forceinline__ void stage32(short* slot, const short* gbase, int ld,
                                        int tid, int wave) {
#pragma unroll
  for (int j = 0; j < 2; ++j) {
    const int o = j * 8192 + tid * 16;          // linear LDS byte offset in slot
    const int r = o >> 6;                       // slot row (0..255)
    const int cb = (o & 63) ^ ((r & 3) << 4);   // pre-swizzled source col-byte
    __builtin_amdgcn_global_load_lds(
        (const __attribute__((address_space(1))) void*)(gbase + (size_t)r * ld + (cb >> 1)),
        (__attribute__((address_space(3))) void*)((char*)slot + j * 8192 + wave * 1024),
        16, 0, 0);
  }
}

template <typename SFn>
__device__ __forceinline__ void ktile32(const short (*buf)[8192], f32x16 (&acc)[4][2],
                                        int wr, int wc, int lane, SFn stagefn) {
  stagefn();  // issue next-ring stage first (longest latency)
  const int rl = lane & 31;
  const int khi = (lane >> 5) * 16;  // byte offset of this lane's k-half
  bf16x8 a[2][4], b[2][2];
#pragma unroll
  for (int ks = 0; ks < 2; ++ks) {
#pragma unroll
    for (int tm = 0; tm < 4; ++tm)
      a[ks][tm] = frag32(buf[0], wr * 128 + tm * 32 + rl, ks * 32 + khi);
#pragma unroll
    for (int tn = 0; tn < 2; ++tn)
      b[ks][tn] = frag32(buf[1], wc * 64 + tn * 32 + rl, ks * 32 + khi);
  }
  __builtin_amdgcn_s_setprio(1);
#pragma unroll
  for (int ks = 0; ks < 2; ++ks)
#pragma unroll
    for (int tm = 0; tm < 4; ++tm)
#pragma unroll
      for (int tn = 0; tn < 2; ++tn)
        acc[tm][tn] = __builtin_amdgcn_mfma_f32_32x32x16_bf16(a[ks][tm], b[ks][tn],
                                                              acc[tm][tn], 0, 0, 0);
  __builtin_amdgcn_s_setprio(0);
  asm volatile("s_waitcnt vmcnt(8) lgkmcnt(0)" ::: "memory");
  __builtin_amdgcn_s_barrier();
}

// ---------------- encode: feats[l] = relu(x[l] @ W_enc[l]^T) ----------------

__global__ __launch_bounds__(512, 2) void k_encode256(const short* __restrict__ xbf,
                                                      const short* __restrict__ webf,
                                                      float* __restrict__ feats_f32,
                                                      short* __restrict__ feats_bf) {
  __shared__ short lds[4][2][8192];
  const int l = blockIdx.z;
  const int row0 = blockIdx.y * 256;  // T
  const int col0 = blockIdx.x * 256;  // F
  const int tid = threadIdx.x;
  const int wave = tid >> 6, lane = tid & 63;
  const int wr = wave >> 2, wc = wave & 3;

  const short* A = xbf + (size_t)l * NT * NH + (size_t)row0 * NH;
  const short* B = webf + (size_t)l * NF * NH + (size_t)col0 * NH;

  f32x16 acc[4][2];
#pragma unroll
  for (int tm = 0; tm < 4; ++tm)
#pragma unroll
    for (int tn = 0; tn < 2; ++tn)
#pragma unroll
      for (int q = 0; q < 16; ++q) acc[tm][tn][q] = 0.f;

  const int KT = NH / 32;  // 64
#pragma unroll
  for (int t = 0; t < 3; ++t) {
    stage32(lds[t][0], A + t * 32, NH, tid, wave);
    stage32(lds[t][1], B + t * 32, NH, tid, wave);
  }
  asm volatile("s_waitcnt vmcnt(8)" ::: "memory");
  __builtin_amdgcn_s_barrier();

  for (int u = 0; u < KT; ++u) {
    ktile32(lds[u & 3], acc, wr, wc, lane, [&] {
      const int t = imin(u + 3, KT - 1);
      stage32(lds[(u + 3) & 3][0], A + t * 32, NH, tid, wave);
      stage32(lds[(u + 3) & 3][1], B + t * 32, NH, tid, wave);
    });
  }

  const int rl = lane & 31, lhi = (lane >> 5) * 4;
  float* outF = feats_f32 + (size_t)l * NT * NF;
  short* outB = feats_bf + (size_t)l * NT * NF;
#pragma unroll
  for (int tm = 0; tm < 4; ++tm)
#pragma unroll
    for (int tn = 0; tn < 2; ++tn)
#pragma unroll
      for (int q = 0; q < 16; ++q) {
        const int rr = row0 + wr * 128 + tm * 32 + (q & 3) + 8 * (q >> 2) + lhi;
        const int cc = col0 + wc * 64 + tn * 32 + rl;
        float v = acc[tm][tn][q];
        v = v > 0.f ? v : 0.f;
        outF[(size_t)rr * NF + cc] = v;
        outB[(size_t)rr * NF + cc] = f2bf(v);
      }
}

// ---------------- decode: recon[l] = sum_{s<=l} feats[s] @ W_dec[s,l]^T ----------------

__global__ __launch_bounds__(512, 2) void k_decode256(const short* __restrict__ featsbf,
                                                      const short* __restrict__ wdbf,
                                                      float* __restrict__ recon) {
  __shared__ short lds[4][2][8192];
  const int l = (NL - 1) - blockIdx.z;  // heavy-first (LPT under in-order dispatch)
  const int row0 = blockIdx.y * 256;    // T
  const int col0 = blockIdx.x * 256;    // H
  const int tid = threadIdx.x;
  const int wave = tid >> 6, lane = tid & 63;
  const int wr = wave >> 2, wc = wave & 3;
  const int pbase = l * (l + 1) / 2;

  const short* Af = featsbf + (size_t)row0 * NF;
  const short* Bw = wdbf + (size_t)col0 * NF;

  f32x16 acc[4][2];
#pragma unroll
  for (int tm = 0; tm < 4; ++tm)
#pragma unroll
    for (int tn = 0; tn < 2; ++tn)
#pragma unroll
      for (int q = 0; q < 16; ++q) acc[tm][tn][q] = 0.f;

  const int KT = 16 * (l + 1);  // BK=32 tiles
#define ABASE(t) (Af + (size_t)((t) >> 4) * (NT * NF) + ((t)&15) * 32)
#define BBASE(t) (Bw + (size_t)(pbase + ((t) >> 4)) * (NH * NF) + ((t)&15) * 32)

#pragma unroll
  for (int t = 0; t < 3; ++t) {
    stage32(lds[t][0], ABASE(t), NF, tid, wave);
    stage32(lds[t][1], BBASE(t), NF, tid, wave);
  }
  asm volatile("s_waitcnt vmcnt(8)" ::: "memory");
  __builtin_amdgcn_s_barrier();

  for (int u = 0; u < KT; ++u) {
    ktile32(lds[u & 3], acc, wr, wc, lane, [&] {
      const int t = imin(u + 3, KT - 1);
      stage32(lds[(u + 3) & 3][0], ABASE(t), NF, tid, wave);
      stage32(lds[(u + 3) & 3][1], BBASE(t), NF, tid, wave);
    });
  }
#undef ABASE
#undef BBASE

  const int rl = lane & 31, lhi = (lane >> 5) * 4;
  float* out = recon + (size_t)l * NT * NH;
#pragma unroll
  for (int tm = 0; tm < 4; ++tm)
#pragma unroll
    for (int tn = 0; tn < 2; ++tn)
#pragma unroll
      for (int q = 0; q < 16; ++q) {
        const int rr = row0 + wr * 128 + tm * 32 + (q & 3) + 8 * (q >> 2) + lhi;
        const int cc = col0 + wc * 64 + tn * 32 + rl;
        out[(size_t)rr * NH + cc] = acc[tm][tn][q];
      }
}

// ---------------- launch ----------------

extern "C" void kernel_launch(void* const* d_in, const int* in_sizes, int n_in,
                              void* d_out, int out_size, void* d_ws, size_t ws_size,
                              hipStream_t stream) {
  const float* x = (const float*)d_in[0];
  const float* wenc = (const float*)d_in[1];
  const float* wdec = (const float*)d_in[2];

  float* feats_f32 = (float*)d_out;
  float* recon = feats_f32 + (size_t)NL * NT * NF;

  short* x_bf = (short*)d_ws;
  short* we_bf = x_bf + (size_t)NL * NT * NH;
  short* wd_bf = we_bf + (size_t)NL * NF * NH;
  short* ft_bf = wd_bf + (size_t)NPAIR * NH * NF;

  k_cvt_f32_bf16<<<2048, 256, 0, stream>>>(x, x_bf, NL * NT * NH / 4);
  k_cvt_f32_bf16<<<2048, 256, 0, stream>>>(wenc, we_bf, NL * NF * NH / 4);
  k_cvt_wdec<<<dim3(512, NPAIR), 256, 0, stream>>>(wdec, wd_bf);

  k_encode256<<<dim3(2, 8, 16), 512, 0, stream>>>(x_bf, we_bf, feats_f32, ft_bf);
  k_decode256<<<dim3(8, 8, 16), 512, 0, stream>>>(ft_bf, wd_bf, recon);
}

// Round 7
// 926.740 us; speedup vs baseline: 1.0732x; 1.0732x over previous
//
#include <hip/hip_runtime.h>

#define NL 16
#define NT 2048
#define NH 2048
#define NF 512
#define NPAIR 136

typedef short bf16x8 __attribute__((ext_vector_type(8)));
typedef float f32x16 __attribute__((ext_vector_type(16)));
typedef short s16x4 __attribute__((ext_vector_type(4)));

__device__ __forceinline__ short f2bf(float f) {
  union { float f; unsigned u; } x; x.f = f;
  unsigned r = (x.u + 0x7fffu + ((x.u >> 16) & 1u)) >> 16;
  return (short)r;
}

__device__ __forceinline__ int imin(int a, int b) { return a < b ? a : b; }

// ---------------- conversion kernels ----------------

__global__ void k_cvt_f32_bf16(const float* __restrict__ src, short* __restrict__ dst, int n4) {
  int i = blockIdx.x * blockDim.x + threadIdx.x;
  const int stride = gridDim.x * blockDim.x;
  for (; i < n4; i += stride) {
    const float4 v = reinterpret_cast<const float4*>(src)[i];
    s16x4 o;
    o[0] = f2bf(v.x); o[1] = f2bf(v.y); o[2] = f2bf(v.z); o[3] = f2bf(v.w);
    reinterpret_cast<s16x4*>(dst)[i] = o;
  }
}

__global__ void k_cvt_wdec(const float* __restrict__ wdec, short* __restrict__ dst) {
  const int p = blockIdx.y;
  int l = 0;
  while ((l + 1) * (l + 2) / 2 <= p) ++l;
  const int s = p - l * (l + 1) / 2;
  const float* src = wdec + (size_t)(s * NL + l) * (NH * NF);
  short* d = dst + (size_t)p * (NH * NF);
  const int n4 = NH * NF / 4;
  for (int i = blockIdx.x * blockDim.x + threadIdx.x; i < n4; i += gridDim.x * blockDim.x) {
    const float4 v = reinterpret_cast<const float4*>(src)[i];
    s16x4 o;
    o[0] = f2bf(v.x); o[1] = f2bf(v.y); o[2] = f2bf(v.z); o[3] = f2bf(v.w);
    reinterpret_cast<s16x4*>(d)[i] = o;
  }
}

// ---------------- 256x256 GEMM, BK=64, 2-buf, 32x32x16 MFMA ----------------
// 8 waves: wr=wave>>2 (2 row-groups of 128), wc=wave&3 (4 col-groups of 64).
// Per-wave output 128x64 = tm(4) x tn(2) tiles of 32x32, acc f32x16 each.
// LDS: lds[buf][slot][8192 shorts]; slot 0=A-half0, 1=A-half1, 2=B-half0, 3=B-half1.
//   A-half(h) local row r (0..127) <-> global tile row (r>>6)*128 + h*64 + (r&63)
//   B-half(h) local row r (0..127) <-> global tile row (r>>5)*64  + h*32 + (r&31)
//   => a(tm) lives in slot (tm>>1) at local row wr*64 + (tm&1)*32 + rl
//      b(tn) lives in slot (2+tn) at local row wc*32 + rl          (rl=lane&31)
// Swizzle: element (r, cbyte) at LDS byte ((r<<7)|cbyte) ^ ((r&7)<<4)  — bank-
// balanced for 32-row x 16B fragment reads (each 16B slot-position gets 128B).
// Phases per K-tile u (stage schedule + ledger == round-5, proven):
//   p0 reads slots {0,2} (12 frags); stages bufn[3] (B1 of u+1)
//   p1 reads slot {3}    (4);        stages bufn[1] (A1 of u+1)
//   p2 reads slot {1}    (8);        stages bufc[0] (A0 of u+2)   [last read p0]
//   p3 reads {}          (0);        stages bufc[2] (B0 of u+2)   [last read p0]
// Each phase ends: s_waitcnt vmcnt(8); s_barrier.  Tail stages clamp to KT-1.

__device__ __forceinline__ bf16x8 lds_frag(const short* slot, int r, int cbyte) {
  int byte = (r << 7) + cbyte;
  byte ^= (r & 7) << 4;
  return *reinterpret_cast<const bf16x8*>(reinterpret_cast<const char*>(slot) + byte);
}

__device__ __forceinline__ void stage_half(short* slot, const short* gbase, int ld,
                                           int isA, int h, int tid, int wave) {
#pragma unroll
  for (int j = 0; j < 2; ++j) {
    const int o = j * 8192 + tid * 16;              // linear LDS byte offset in slot
    const int r = o >> 7;                           // slot-local row
    const int cb = (o ^ ((r & 7) << 4)) & 127;      // pre-swizzled source col-byte
    const int g = isA ? (((r >> 6) << 7) + h * 64 + (r & 63))
                      : (((r >> 5) << 6) + h * 32 + (r & 31));
    __builtin_amdgcn_global_load_lds(
        (const __attribute__((address_space(1))) void*)(gbase + (size_t)g * ld + (cb >> 1)),
        (__attribute__((address_space(3))) void*)((char*)slot + j * 8192 + wave * 1024),
        16, 0, 0);
  }
}

__device__ __forceinline__ void phase_end() {
  asm volatile("s_waitcnt vmcnt(8)" ::: "memory");
  __builtin_amdgcn_s_barrier();
}

template <typename S0, typename S1, typename S2, typename S3>
__device__ __forceinline__ void ktile(short (*bufc)[8192], f32x16 (&acc)[4][2],
                                      int wr, int wc, int lane,
                                      S0 s0, S1 s1, S2 s2, S3 s3) {
  const int rl = lane & 31;
  const int khi = (lane >> 5) * 16;  // byte offset of this lane's k-half
  bf16x8 aA[4][2], aB[4][2], b0[4], b1[4];  // [ks][tm-within-pair]
  // ---- p0: read a(tm=0,1) from slot0 + b(tn=0) from slot2 ; mfma tm01 x tn0
  s0();
#pragma unroll
  for (int ks = 0; ks < 4; ++ks) {
    aA[ks][0] = lds_frag(bufc[0], wr * 64 + rl, ks * 32 + khi);
    aA[ks][1] = lds_frag(bufc[0], wr * 64 + 32 + rl, ks * 32 + khi);
    b0[ks] = lds_frag(bufc[2], wc * 32 + rl, ks * 32 + khi);
  }
  __builtin_amdgcn_s_setprio(1);
#pragma unroll
  for (int ks = 0; ks < 4; ++ks) {
    acc[0][0] = __builtin_amdgcn_mfma_f32_32x32x16_bf16(aA[ks][0], b0[ks], acc[0][0], 0, 0, 0);
    acc[1][0] = __builtin_amdgcn_mfma_f32_32x32x16_bf16(aA[ks][1], b0[ks], acc[1][0], 0, 0, 0);
  }
  __builtin_amdgcn_s_setprio(0);
  phase_end();
  // ---- p1: read b(tn=1) from slot3 ; mfma tm01 x tn1
  s1();
#pragma unroll
  for (int ks = 0; ks < 4; ++ks)
    b1[ks] = lds_frag(bufc[3], wc * 32 + rl, ks * 32 + khi);
  __builtin_amdgcn_s_setprio(1);
#pragma unroll
  for (int ks = 0; ks < 4; ++ks) {
    acc[0][1] = __builtin_amdgcn_mfma_f32_32x32x16_bf16(aA[ks][0], b1[ks], acc[0][1], 0, 0, 0);
    acc[1][1] = __builtin_amdgcn_mfma_f32_32x32x16_bf16(aA[ks][1], b1[ks], acc[1][1], 0, 0, 0);
  }
  __builtin_amdgcn_s_setprio(0);
  phase_end();
  // ---- p2: read a(tm=2,3) from slot1 ; mfma tm23 x tn0
  s2();
#pragma unroll
  for (int ks = 0; ks < 4; ++ks) {
    aB[ks][0] = lds_frag(bufc[1], wr * 64 + rl, ks * 32 + khi);
    aB[ks][1] = lds_frag(bufc[1], wr * 64 + 32 + rl, ks * 32 + khi);
  }
  __builtin_amdgcn_s_setprio(1);
#pragma unroll
  for (int ks = 0; ks < 4; ++ks) {
    acc[2][0] = __builtin_amdgcn_mfma_f32_32x32x16_bf16(aB[ks][0], b0[ks], acc[2][0], 0, 0, 0);
    acc[3][0] = __builtin_amdgcn_mfma_f32_32x32x16_bf16(aB[ks][1], b0[ks], acc[3][0], 0, 0, 0);
  }
  __builtin_amdgcn_s_setprio(0);
  phase_end();
  // ---- p3: no reads ; mfma tm23 x tn1
  s3();
  __builtin_amdgcn_s_setprio(1);
#pragma unroll
  for (int ks = 0; ks < 4; ++ks) {
    acc[2][1] = __builtin_amdgcn_mfma_f32_32x32x16_bf16(aB[ks][0], b1[ks], acc[2][1], 0, 0, 0);
    acc[3][1] = __builtin_amdgcn_mfma_f32_32x32x16_bf16(aB[ks][1], b1[ks], acc[3][1], 0, 0, 0);
  }
  __builtin_amdgcn_s_setprio(0);
  phase_end();
}

// ---------------- encode: feats[l] = relu(x[l] @ W_enc[l]^T) ----------------

__global__ __launch_bounds__(512, 2) void k_encode256(const short* __restrict__ xbf,
                                                      const short* __restrict__ webf,
                                                      float* __restrict__ feats_f32,
                                                      short* __restrict__ feats_bf) {
  __shared__ short lds[2][4][8192];
  const int l = blockIdx.z;
  const int row0 = blockIdx.y * 256;  // T
  const int col0 = blockIdx.x * 256;  // F
  const int tid = threadIdx.x;
  const int wave = tid >> 6, lane = tid & 63;
  const int wr = wave >> 2, wc = wave & 3;

  const short* A = xbf + (size_t)l * NT * NH + (size_t)row0 * NH;
  const short* B = webf + (size_t)l * NF * NH + (size_t)col0 * NH;

  f32x16 acc[4][2];
#pragma unroll
  for (int tm = 0; tm < 4; ++tm)
#pragma unroll
    for (int tn = 0; tn < 2; ++tn)
#pragma unroll
      for (int q = 0; q < 16; ++q) acc[tm][tn][q] = 0.f;

  const int KT = NH / 64;  // 32
  stage_half(lds[0][0], A, NH, 1, 0, tid, wave);
  stage_half(lds[0][2], B, NH, 0, 0, tid, wave);
  stage_half(lds[0][1], A, NH, 1, 1, tid, wave);
  stage_half(lds[0][3], B, NH, 0, 1, tid, wave);
  stage_half(lds[1][0], A + 64, NH, 1, 0, tid, wave);
  stage_half(lds[1][2], B + 64, NH, 0, 0, tid, wave);
  asm volatile("s_waitcnt vmcnt(4)" ::: "memory");
  __builtin_amdgcn_s_barrier();

  for (int u = 0; u < KT; ++u) {
    short(*bufc)[8192] = lds[u & 1];
    short(*bufn)[8192] = lds[(u + 1) & 1];
    ktile(bufc, acc, wr, wc, lane,
          [&] { stage_half(bufn[3], B + imin(u + 1, KT - 1) * 64, NH, 0, 1, tid, wave); },
          [&] { stage_half(bufn[1], A + imin(u + 1, KT - 1) * 64, NH, 1, 1, tid, wave); },
          [&] { stage_half(bufc[0], A + imin(u + 2, KT - 1) * 64, NH, 1, 0, tid, wave); },
          [&] { stage_half(bufc[2], B + imin(u + 2, KT - 1) * 64, NH, 0, 0, tid, wave); });
  }

  const int rl = lane & 31, lhi = (lane >> 5) * 4;
  float* outF = feats_f32 + (size_t)l * NT * NF;
  short* outB = feats_bf + (size_t)l * NT * NF;
#pragma unroll
  for (int tm = 0; tm < 4; ++tm)
#pragma unroll
    for (int tn = 0; tn < 2; ++tn)
#pragma unroll
      for (int q = 0; q < 16; ++q) {
        const int rr = row0 + wr * 128 + tm * 32 + (q & 3) + 8 * (q >> 2) + lhi;
        const int cc = col0 + wc * 64 + tn * 32 + rl;
        float v = acc[tm][tn][q];
        v = v > 0.f ? v : 0.f;
        outF[(size_t)rr * NF + cc] = v;
        outB[(size_t)rr * NF + cc] = f2bf(v);
      }
}

// ---------------- decode: recon[l] = sum_{s<=l} feats[s] @ W_dec[s,l]^T ----------------

__global__ __launch_bounds__(512, 2) void k_decode256(const short* __restrict__ featsbf,
                                                      const short* __restrict__ wdbf,
                                                      float* __restrict__ recon) {
  __shared__ short lds[2][4][8192];
  const int l = (NL - 1) - blockIdx.z;  // heavy-first (LPT under in-order dispatch)
  const int row0 = blockIdx.y * 256;    // T
  const int col0 = blockIdx.x * 256;    // H
  const int tid = threadIdx.x;
  const int wave = tid >> 6, lane = tid & 63;
  const int wr = wave >> 2, wc = wave & 3;
  const int pbase = l * (l + 1) / 2;

  const short* Af = featsbf + (size_t)row0 * NF;
  const short* Bw = wdbf + (size_t)col0 * NF;

  f32x16 acc[4][2];
#pragma unroll
  for (int tm = 0; tm < 4; ++tm)
#pragma unroll
    for (int tn = 0; tn < 2; ++tn)
#pragma unroll
      for (int q = 0; q < 16; ++q) acc[tm][tn][q] = 0.f;

  const int KT = 8 * (l + 1);
#define ABASE(kt) (Af + (size_t)((kt) >> 3) * (NT * NF) + ((kt)&7) * 64)
#define BBASE(kt) (Bw + (size_t)(pbase + ((kt) >> 3)) * (NH * NF) + ((kt)&7) * 64)

  stage_half(lds[0][0], ABASE(0), NF, 1, 0, tid, wave);
  stage_half(lds[0][2], BBASE(0), NF, 0, 0, tid, wave);
  stage_half(lds[0][1], ABASE(0), NF, 1, 1, tid, wave);
  stage_half(lds[0][3], BBASE(0), NF, 0, 1, tid, wave);
  stage_half(lds[1][0], ABASE(1), NF, 1, 0, tid, wave);
  stage_half(lds[1][2], BBASE(1), NF, 0, 0, tid, wave);
  asm volatile("s_waitcnt vmcnt(4)" ::: "memory");
  __builtin_amdgcn_s_barrier();

  for (int u = 0; u < KT; ++u) {
    short(*bufc)[8192] = lds[u & 1];
    short(*bufn)[8192] = lds[(u + 1) & 1];
    ktile(bufc, acc, wr, wc, lane,
          [&] { stage_half(bufn[3], BBASE(imin(u + 1, KT - 1)), NF, 0, 1, tid, wave); },
          [&] { stage_half(bufn[1], ABASE(imin(u + 1, KT - 1)), NF, 1, 1, tid, wave); },
          [&] { stage_half(bufc[0], ABASE(imin(u + 2, KT - 1)), NF, 1, 0, tid, wave); },
          [&] { stage_half(bufc[2], BBASE(imin(u + 2, KT - 1)), NF, 0, 0, tid, wave); });
  }
#undef ABASE
#undef BBASE

  const int rl = lane & 31, lhi = (lane >> 5) * 4;
  float* out = recon + (size_t)l * NT * NH;
#pragma unroll
  for (int tm = 0; tm < 4; ++tm)
#pragma unroll
    for (int tn = 0; tn < 2; ++tn)
#pragma unroll
      for (int q = 0; q < 16; ++q) {
        const int rr = row0 + wr * 128 + tm * 32 + (q & 3) + 8 * (q >> 2) + lhi;
        const int cc = col0 + wc * 64 + tn * 32 + rl;
        out[(size_t)rr * NH + cc] = acc[tm][tn][q];
      }
}

// ---------------- launch ----------------

extern "C" void kernel_launch(void* const* d_in, const int* in_sizes, int n_in,
                              void* d_out, int out_size, void* d_ws, size_t ws_size,
                              hipStream_t stream) {
  const float* x = (const float*)d_in[0];
  const float* wenc = (const float*)d_in[1];
  const float* wdec = (const float*)d_in[2];

  float* feats_f32 = (float*)d_out;
  float* recon = feats_f32 + (size_t)NL * NT * NF;

  short* x_bf = (short*)d_ws;
  short* we_bf = x_bf + (size_t)NL * NT * NH;
  short* wd_bf = we_bf + (size_t)NL * NF * NH;
  short* ft_bf = wd_bf + (size_t)NPAIR * NH * NF;

  k_cvt_f32_bf16<<<2048, 256, 0, stream>>>(x, x_bf, NL * NT * NH / 4);
  k_cvt_f32_bf16<<<2048, 256, 0, stream>>>(wenc, we_bf, NL * NF * NH / 4);
  k_cvt_wdec<<<dim3(512, NPAIR), 256, 0, stream>>>(wdec, wd_bf);

  k_encode256<<<dim3(2, 8, 16), 512, 0, stream>>>(x_bf, we_bf, feats_f32, ft_bf);
  k_decode256<<<dim3(8, 8, 16), 512, 0, stream>>>(ft_bf, wd_bf, recon);
}

// Round 8
// 902.517 us; speedup vs baseline: 1.1020x; 1.0268x over previous
//
#include <hip/hip_runtime.h>

#define NL 16
#define NT 2048
#define NH 2048
#define NF 512
#define NPAIR 136

typedef short bf16x8 __attribute__((ext_vector_type(8)));
typedef float f32x4 __attribute__((ext_vector_type(4)));
typedef float f32x16 __attribute__((ext_vector_type(16)));
typedef short s16x4 __attribute__((ext_vector_type(4)));

__device__ __forceinline__ short f2bf(float f) {
  union { float f; unsigned u; } x; x.f = f;
  unsigned r = (x.u + 0x7fffu + ((x.u >> 16) & 1u)) >> 16;
  return (short)r;
}

__device__ __forceinline__ int imin(int a, int b) { return a < b ? a : b; }

// ---------------- conversion kernels ----------------

__global__ void k_cvt_f32_bf16(const float* __restrict__ src, short* __restrict__ dst, int n4) {
  int i = blockIdx.x * blockDim.x + threadIdx.x;
  const int stride = gridDim.x * blockDim.x;
  for (; i < n4; i += stride) {
    const float4 v = reinterpret_cast<const float4*>(src)[i];
    s16x4 o;
    o[0] = f2bf(v.x); o[1] = f2bf(v.y); o[2] = f2bf(v.z); o[3] = f2bf(v.w);
    reinterpret_cast<s16x4*>(dst)[i] = o;
  }
}

__global__ void k_cvt_wdec(const float* __restrict__ wdec, short* __restrict__ dst) {
  const int p = blockIdx.y;
  int l = 0;
  while ((l + 1) * (l + 2) / 2 <= p) ++l;
  const int s = p - l * (l + 1) / 2;
  const float* src = wdec + (size_t)(s * NL + l) * (NH * NF);
  short* d = dst + (size_t)p * (NH * NF);
  const int n4 = NH * NF / 4;
  for (int i = blockIdx.x * blockDim.x + threadIdx.x; i < n4; i += gridDim.x * blockDim.x) {
    const float4 v = reinterpret_cast<const float4*>(src)[i];
    s16x4 o;
    o[0] = f2bf(v.x); o[1] = f2bf(v.y); o[2] = f2bf(v.z); o[3] = f2bf(v.w);
    reinterpret_cast<s16x4*>(d)[i] = o;
  }
}

// ---------------- shared 256x256 staging machinery (proven r5 ledger) ----------------
// LDS: lds[buf][slot][8192 shorts]; slot 0=A-half0, 1=A-half1, 2=B-half0, 3=B-half1.
//   A-half(h) local row r (0..127) <-> global tile row (r>>6)*128 + h*64 + (r&63)
//   B-half(h) local row r (0..127) <-> global tile row (r>>5)*64  + h*32 + (r&31)
// Swizzle: element (r, cbyte) at LDS byte ((r<<7)|cbyte) ^ ((r&7)<<4).
// Phase stage schedule per K-tile u (p0..p3), each phase ends vmcnt(8)+barrier:
//   p0 stages bufn[3]=B1(u+1); p1 stages bufn[1]=A1(u+1);
//   p2 stages bufc[0]=A0(u+2); p3 stages bufc[2]=B0(u+2).  Tail clamps to KT-1.

__device__ __forceinline__ bf16x8 lds_frag(const short* slot, int r, int cbyte) {
  int byte = (r << 7) + cbyte;
  byte ^= (r & 7) << 4;
  return *reinterpret_cast<const bf16x8*>(reinterpret_cast<const char*>(slot) + byte);
}

__device__ __forceinline__ void stage_half(short* slot, const short* gbase, int ld,
                                           int isA, int h, int tid, int wave) {
#pragma unroll
  for (int j = 0; j < 2; ++j) {
    const int o = j * 8192 + tid * 16;              // linear LDS byte offset in slot
    const int r = o >> 7;                           // slot-local row
    const int cb = (o ^ ((r & 7) << 4)) & 127;      // pre-swizzled source col-byte
    const int g = isA ? (((r >> 6) << 7) + h * 64 + (r & 63))
                      : (((r >> 5) << 6) + h * 32 + (r & 31));
    __builtin_amdgcn_global_load_lds(
        (const __attribute__((address_space(1))) void*)(gbase + (size_t)g * ld + (cb >> 1)),
        (__attribute__((address_space(3))) void*)((char*)slot + j * 8192 + wave * 1024),
        16, 0, 0);
  }
}

__device__ __forceinline__ void phase_end() {
  asm volatile("s_waitcnt vmcnt(8)" ::: "memory");
  __builtin_amdgcn_s_barrier();
}

// ---- 16x16 ktile (round-5 proven; used by encode) ----
template <typename S0, typename S1, typename S2, typename S3>
__device__ __forceinline__ void ktile16(short (*bufc)[8192], f32x4 (&acc)[2][2][4][2],
                                        int wr, int wc, int lane,
                                        S0 s0, S1 s1, S2 s2, S3 s3) {
  const int lr = lane & 15;
  const int ko = (lane >> 4) * 16;
  bf16x8 a0[2][4], a1[2][4], b0[2][2], b1[2][2];
  s0();
#pragma unroll
  for (int kk = 0; kk < 2; ++kk) {
#pragma unroll
    for (int m = 0; m < 4; ++m)
      a0[kk][m] = lds_frag(bufc[0], wr * 64 + m * 16 + lr, kk * 64 + ko);
#pragma unroll
    for (int n = 0; n < 2; ++n)
      b0[kk][n] = lds_frag(bufc[2], wc * 32 + n * 16 + lr, kk * 64 + ko);
  }
  __builtin_amdgcn_s_setprio(1);
#pragma unroll
  for (int kk = 0; kk < 2; ++kk)
#pragma unroll
    for (int m = 0; m < 4; ++m)
#pragma unroll
      for (int n = 0; n < 2; ++n)
        acc[0][0][m][n] = __builtin_amdgcn_mfma_f32_16x16x32_bf16(a0[kk][m], b0[kk][n],
                                                                  acc[0][0][m][n], 0, 0, 0);
  __builtin_amdgcn_s_setprio(0);
  phase_end();
  s1();
#pragma unroll
  for (int kk = 0; kk < 2; ++kk)
#pragma unroll
    for (int n = 0; n < 2; ++n)
      b1[kk][n] = lds_frag(bufc[3], wc * 32 + n * 16 + lr, kk * 64 + ko);
  __builtin_amdgcn_s_setprio(1);
#pragma unroll
  for (int kk = 0; kk < 2; ++kk)
#pragma unroll
    for (int m = 0; m < 4; ++m)
#pragma unroll
      for (int n = 0; n < 2; ++n)
        acc[0][1][m][n] = __builtin_amdgcn_mfma_f32_16x16x32_bf16(a0[kk][m], b1[kk][n],
                                                                  acc[0][1][m][n], 0, 0, 0);
  __builtin_amdgcn_s_setprio(0);
  phase_end();
  s2();
#pragma unroll
  for (int kk = 0; kk < 2; ++kk)
#pragma unroll
    for (int m = 0; m < 4; ++m)
      a1[kk][m] = lds_frag(bufc[1], wr * 64 + m * 16 + lr, kk * 64 + ko);
  __builtin_amdgcn_s_setprio(1);
#pragma unroll
  for (int kk = 0; kk < 2; ++kk)
#pragma unroll
    for (int m = 0; m < 4; ++m)
#pragma unroll
      for (int n = 0; n < 2; ++n)
        acc[1][0][m][n] = __builtin_amdgcn_mfma_f32_16x16x32_bf16(a1[kk][m], b0[kk][n],
                                                                  acc[1][0][m][n], 0, 0, 0);
  __builtin_amdgcn_s_setprio(0);
  phase_end();
  s3();
  __builtin_amdgcn_s_setprio(1);
#pragma unroll
  for (int kk = 0; kk < 2; ++kk)
#pragma unroll
    for (int m = 0; m < 4; ++m)
#pragma unroll
      for (int n = 0; n < 2; ++n)
        acc[1][1][m][n] = __builtin_amdgcn_mfma_f32_16x16x32_bf16(a1[kk][m], b1[kk][n],
                                                                  acc[1][1][m][n], 0, 0, 0);
  __builtin_amdgcn_s_setprio(0);
  phase_end();
}

// ---- 32x32 ktile (round-7 proven; used by decode) ----
template <typename S0, typename S1, typename S2, typename S3>
__device__ __forceinline__ void ktile32(short (*bufc)[8192], f32x16 (&acc)[4][2],
                                        int wr, int wc, int lane,
                                        S0 s0, S1 s1, S2 s2, S3 s3) {
  const int rl = lane & 31;
  const int khi = (lane >> 5) * 16;
  bf16x8 aA[4][2], aB[4][2], b0[4], b1[4];
  s0();
#pragma unroll
  for (int ks = 0; ks < 4; ++ks) {
    aA[ks][0] = lds_frag(bufc[0], wr * 64 + rl, ks * 32 + khi);
    aA[ks][1] = lds_frag(bufc[0], wr * 64 + 32 + rl, ks * 32 + khi);
    b0[ks] = lds_frag(bufc[2], wc * 32 + rl, ks * 32 + khi);
  }
  __builtin_amdgcn_s_setprio(1);
#pragma unroll
  for (int ks = 0; ks < 4; ++ks) {
    acc[0][0] = __builtin_amdgcn_mfma_f32_32x32x16_bf16(aA[ks][0], b0[ks], acc[0][0], 0, 0, 0);
    acc[1][0] = __builtin_amdgcn_mfma_f32_32x32x16_bf16(aA[ks][1], b0[ks], acc[1][0], 0, 0, 0);
  }
  __builtin_amdgcn_s_setprio(0);
  phase_end();
  s1();
#pragma unroll
  for (int ks = 0; ks < 4; ++ks)
    b1[ks] = lds_frag(bufc[3], wc * 32 + rl, ks * 32 + khi);
  __builtin_amdgcn_s_setprio(1);
#pragma unroll
  for (int ks = 0; ks < 4; ++ks) {
    acc[0][1] = __builtin_amdgcn_mfma_f32_32x32x16_bf16(aA[ks][0], b1[ks], acc[0][1], 0, 0, 0);
    acc[1][1] = __builtin_amdgcn_mfma_f32_32x32x16_bf16(aA[ks][1], b1[ks], acc[1][1], 0, 0, 0);
  }
  __builtin_amdgcn_s_setprio(0);
  phase_end();
  s2();
#pragma unroll
  for (int ks = 0; ks < 4; ++ks) {
    aB[ks][0] = lds_frag(bufc[1], wr * 64 + rl, ks * 32 + khi);
    aB[ks][1] = lds_frag(bufc[1], wr * 64 + 32 + rl, ks * 32 + khi);
  }
  __builtin_amdgcn_s_setprio(1);
#pragma unroll
  for (int ks = 0; ks < 4; ++ks) {
    acc[2][0] = __builtin_amdgcn_mfma_f32_32x32x16_bf16(aB[ks][0], b0[ks], acc[2][0], 0, 0, 0);
    acc[3][0] = __builtin_amdgcn_mfma_f32_32x32x16_bf16(aB[ks][1], b0[ks], acc[3][0], 0, 0, 0);
  }
  __builtin_amdgcn_s_setprio(0);
  phase_end();
  s3();
  __builtin_amdgcn_s_setprio(1);
#pragma unroll
  for (int ks = 0; ks < 4; ++ks) {
    acc[2][1] = __builtin_amdgcn_mfma_f32_32x32x16_bf16(aB[ks][0], b1[ks], acc[2][1], 0, 0, 0);
    acc[3][1] = __builtin_amdgcn_mfma_f32_32x32x16_bf16(aB[ks][1], b1[ks], acc[3][1], 0, 0, 0);
  }
  __builtin_amdgcn_s_setprio(0);
  phase_end();
}

// ---------------- encode: feats[l] = relu(x[l] @ W_enc[l]^T) ----------------
// XCD-affinity: d = (p>>3)*64 + r*8 + (p&7), p = l*2+colF. The 8 row-siblings
// of one (l,colF) share d%8 -> same XCD -> W_enc[l] panel L2-resident.

__global__ __launch_bounds__(512, 2) void k_encode256(const short* __restrict__ xbf,
                                                      const short* __restrict__ webf,
                                                      float* __restrict__ feats_f32,
                                                      short* __restrict__ feats_bf) {
  __shared__ short lds[2][4][8192];
  const int d = blockIdx.x;
  const int p = ((d >> 6) << 3) | (d & 7);  // pair 0..31
  const int l = p >> 1;
  const int row0 = ((d >> 3) & 7) * 256;    // T
  const int col0 = (p & 1) * 256;           // F
  const int tid = threadIdx.x;
  const int wave = tid >> 6, lane = tid & 63;
  const int wr = wave >> 2, wc = wave & 3;

  const short* A = xbf + (size_t)l * NT * NH + (size_t)row0 * NH;
  const short* B = webf + (size_t)l * NF * NH + (size_t)col0 * NH;

  f32x4 acc[2][2][4][2];
#pragma unroll
  for (int qa = 0; qa < 2; ++qa)
#pragma unroll
    for (int qb = 0; qb < 2; ++qb)
#pragma unroll
      for (int m = 0; m < 4; ++m)
#pragma unroll
        for (int n = 0; n < 2; ++n) {
          f32x4 z = {0.f, 0.f, 0.f, 0.f};
          acc[qa][qb][m][n] = z;
        }

  const int KT = NH / 64;  // 32
  stage_half(lds[0][0], A, NH, 1, 0, tid, wave);
  stage_half(lds[0][2], B, NH, 0, 0, tid, wave);
  stage_half(lds[0][1], A, NH, 1, 1, tid, wave);
  stage_half(lds[0][3], B, NH, 0, 1, tid, wave);
  stage_half(lds[1][0], A + 64, NH, 1, 0, tid, wave);
  stage_half(lds[1][2], B + 64, NH, 0, 0, tid, wave);
  asm volatile("s_waitcnt vmcnt(4)" ::: "memory");
  __builtin_amdgcn_s_barrier();

  for (int u = 0; u < KT; ++u) {
    short(*bufc)[8192] = lds[u & 1];
    short(*bufn)[8192] = lds[(u + 1) & 1];
    ktile16(bufc, acc, wr, wc, lane,
            [&] { stage_half(bufn[3], B + imin(u + 1, KT - 1) * 64, NH, 0, 1, tid, wave); },
            [&] { stage_half(bufn[1], A + imin(u + 1, KT - 1) * 64, NH, 1, 1, tid, wave); },
            [&] { stage_half(bufc[0], A + imin(u + 2, KT - 1) * 64, NH, 1, 0, tid, wave); },
            [&] { stage_half(bufc[2], B + imin(u + 2, KT - 1) * 64, NH, 0, 0, tid, wave); });
  }

  const int lr4 = (lane >> 4) * 4, lc = lane & 15;
  float* outF = feats_f32 + (size_t)l * NT * NF;
  short* outB = feats_bf + (size_t)l * NT * NF;
#pragma unroll
  for (int qa = 0; qa < 2; ++qa)
#pragma unroll
    for (int qb = 0; qb < 2; ++qb)
#pragma unroll
      for (int m = 0; m < 4; ++m)
#pragma unroll
        for (int n = 0; n < 2; ++n)
#pragma unroll
          for (int rg = 0; rg < 4; ++rg) {
            const int rr = row0 + wr * 128 + qa * 64 + m * 16 + lr4 + rg;
            const int cc = col0 + wc * 64 + qb * 32 + n * 16 + lc;
            float v = acc[qa][qb][m][n][rg];
            v = v > 0.f ? v : 0.f;
            outF[(size_t)rr * NF + cc] = v;
            outB[(size_t)rr * NF + cc] = f2bf(v);
          }
}

// ---------------- decode: recon[l] = sum_{s<=l} feats[s] @ W_dec[s,l]^T ----------------
// XCD-affinity: d = g*64 + r*8 + x with l=15-g (heavy-first), col-block=x,
// row-block=r. The 8 row-siblings of one (l,col) share d%8 -> same XCD ->
// each staged W_dec K-tile (32KB) gets 1 L3/HBM miss + 7 L2 hits.

__global__ __launch_bounds__(512, 2) void k_decode256(const short* __restrict__ featsbf,
                                                      const short* __restrict__ wdbf,
                                                      float* __restrict__ recon) {
  __shared__ short lds[2][4][8192];
  const int d = blockIdx.x;
  const int l = 15 - (d >> 6);
  const int row0 = ((d >> 3) & 7) * 256;  // T
  const int col0 = (d & 7) * 256;         // H
  const int tid = threadIdx.x;
  const int wave = tid >> 6, lane = tid & 63;
  const int wr = wave >> 2, wc = wave & 3;
  const int pbase = l * (l + 1) / 2;

  const short* Af = featsbf + (size_t)row0 * NF;
  const short* Bw = wdbf + (size_t)col0 * NF;

  f32x16 acc[4][2];
#pragma unroll
  for (int tm = 0; tm < 4; ++tm)
#pragma unroll
    for (int tn = 0; tn < 2; ++tn)
#pragma unroll
      for (int q = 0; q < 16; ++q) acc[tm][tn][q] = 0.f;

  const int KT = 8 * (l + 1);
#define ABASE(kt) (Af + (size_t)((kt) >> 3) * (NT * NF) + ((kt)&7) * 64)
#define BBASE(kt) (Bw + (size_t)(pbase + ((kt) >> 3)) * (NH * NF) + ((kt)&7) * 64)

  stage_half(lds[0][0], ABASE(0), NF, 1, 0, tid, wave);
  stage_half(lds[0][2], BBASE(0), NF, 0, 0, tid, wave);
  stage_half(lds[0][1], ABASE(0), NF, 1, 1, tid, wave);
  stage_half(lds[0][3], BBASE(0), NF, 0, 1, tid, wave);
  stage_half(lds[1][0], ABASE(1), NF, 1, 0, tid, wave);
  stage_half(lds[1][2], BBASE(1), NF, 0, 0, tid, wave);
  asm volatile("s_waitcnt vmcnt(4)" ::: "memory");
  __builtin_amdgcn_s_barrier();

  for (int u = 0; u < KT; ++u) {
    short(*bufc)[8192] = lds[u & 1];
    short(*bufn)[8192] = lds[(u + 1) & 1];
    ktile32(bufc, acc, wr, wc, lane,
            [&] { stage_half(bufn[3], BBASE(imin(u + 1, KT - 1)), NF, 0, 1, tid, wave); },
            [&] { stage_half(bufn[1], ABASE(imin(u + 1, KT - 1)), NF, 1, 1, tid, wave); },
            [&] { stage_half(bufc[0], ABASE(imin(u + 2, KT - 1)), NF, 1, 0, tid, wave); },
            [&] { stage_half(bufc[2], BBASE(imin(u + 2, KT - 1)), NF, 0, 0, tid, wave); });
  }
#undef ABASE
#undef BBASE

  const int rl = lane & 31, lhi = (lane >> 5) * 4;
  float* out = recon + (size_t)l * NT * NH;
#pragma unroll
  for (int tm = 0; tm < 4; ++tm)
#pragma unroll
    for (int tn = 0; tn < 2; ++tn)
#pragma unroll
      for (int q = 0; q < 16; ++q) {
        const int rr = row0 + wr * 128 + tm * 32 + (q & 3) + 8 * (q >> 2) + lhi;
        const int cc = col0 + wc * 64 + tn * 32 + rl;
        out[(size_t)rr * NH + cc] = acc[tm][tn][q];
      }
}

// ---------------- launch ----------------

extern "C" void kernel_launch(void* const* d_in, const int* in_sizes, int n_in,
                              void* d_out, int out_size, void* d_ws, size_t ws_size,
                              hipStream_t stream) {
  const float* x = (const float*)d_in[0];
  const float* wenc = (const float*)d_in[1];
  const float* wdec = (const float*)d_in[2];

  float* feats_f32 = (float*)d_out;
  float* recon = feats_f32 + (size_t)NL * NT * NF;

  short* x_bf = (short*)d_ws;
  short* we_bf = x_bf + (size_t)NL * NT * NH;
  short* wd_bf = we_bf + (size_t)NL * NF * NH;
  short* ft_bf = wd_bf + (size_t)NPAIR * NH * NF;

  k_cvt_f32_bf16<<<2048, 256, 0, stream>>>(x, x_bf, NL * NT * NH / 4);
  k_cvt_f32_bf16<<<2048, 256, 0, stream>>>(wenc, we_bf, NL * NF * NH / 4);
  k_cvt_wdec<<<dim3(512, NPAIR), 256, 0, stream>>>(wdec, wd_bf);

  k_encode256<<<256, 512, 0, stream>>>(x_bf, we_bf, feats_f32, ft_bf);
  k_decode256<<<1024, 512, 0, stream>>>(ft_bf, wd_bf, recon);
}

// Round 9
// 837.624 us; speedup vs baseline: 1.1873x; 1.0775x over previous
//
#include <hip/hip_runtime.h>

#define NL 16
#define NT 2048
#define NH 2048
#define NF 512
#define NPAIR 136

typedef short bf16x8 __attribute__((ext_vector_type(8)));
typedef float f32x4 __attribute__((ext_vector_type(4)));
typedef short s16x4 __attribute__((ext_vector_type(4)));

__device__ __forceinline__ short f2bf(float f) {
  union { float f; unsigned u; } x; x.f = f;
  unsigned r = (x.u + 0x7fffu + ((x.u >> 16) & 1u)) >> 16;
  return (short)r;
}

__device__ __forceinline__ int imin(int a, int b) { return a < b ? a : b; }

// ---------------- conversion kernels ----------------

__global__ void k_cvt_f32_bf16(const float* __restrict__ src, short* __restrict__ dst, int n4) {
  int i = blockIdx.x * blockDim.x + threadIdx.x;
  const int stride = gridDim.x * blockDim.x;
  for (; i < n4; i += stride) {
    const float4 v = reinterpret_cast<const float4*>(src)[i];
    s16x4 o;
    o[0] = f2bf(v.x); o[1] = f2bf(v.y); o[2] = f2bf(v.z); o[3] = f2bf(v.w);
    reinterpret_cast<s16x4*>(dst)[i] = o;
  }
}

__global__ void k_cvt_wdec(const float* __restrict__ wdec, short* __restrict__ dst) {
  const int p = blockIdx.y;
  int l = 0;
  while ((l + 1) * (l + 2) / 2 <= p) ++l;
  const int s = p - l * (l + 1) / 2;
  const float* src = wdec + (size_t)(s * NL + l) * (NH * NF);
  short* d = dst + (size_t)p * (NH * NF);
  const int n4 = NH * NF / 4;
  for (int i = blockIdx.x * blockDim.x + threadIdx.x; i < n4; i += gridDim.x * blockDim.x) {
    const float4 v = reinterpret_cast<const float4*>(src)[i];
    s16x4 o;
    o[0] = f2bf(v.x); o[1] = f2bf(v.y); o[2] = f2bf(v.z); o[3] = f2bf(v.w);
    reinterpret_cast<s16x4*>(d)[i] = o;
  }
}

// ---------------- 256x256 GEMM (r5 frag-cached ktile, relaxed sync) ----------------
// 8 waves: wr=wave>>2, wc=wave&3. Per-wave out 128x64, quadrants (qa,qb).
// LDS: lds[buf][slot][8192 shorts]; slot 0=A-half0, 1=A-half1, 2=B-half0, 3=B-half1.
//   A-half(h) local row r <-> tile row (r>>6)*128 + h*64 + (r&63)
//   B-half(h) local row r <-> tile row (r>>5)*64  + h*32 + (r&31)
// Swizzle: element (r, cbyte) at LDS byte ((r<<7)|cbyte) ^ ((r&7)<<4).
// K-tile u, 4 sub-phases, frags read ONCE and cached in VGPRs:
//   p0: stage bufn[3]=B1(u+1); read a0(8),b0(4); MFMA q(0,0)
//   p1: stage bufn[1]=A1(u+1); read b1(4);       MFMA q(0,1); BARRIER (bare)
//   p2: stage bufc[2]=B0(u+2); read a1(8);       MFMA q(1,0)
//   p3: stage bufc[0]=A0(u+2);                   MFMA q(1,1); VMCNT(4)+BARRIER
// Sync ledger (verified per-slot, incl. prologue & clamped tail):
//  WAR: every stage's target slot had its last ds_read >=1 barrier earlier
//   (bufn[3]: u-1:p1 reads | u-1:p3 bar; bufn[1]: u-1:p2 | u-1:p3 bar;
//    bufc[2]: u:p0 | u:p1 bar; bufc[0]: u:p0 | u:p1 bar). Reads are consumed
//   by that phase's MFMAs (compiler lgkm-waits) before the wave crosses the bar.
//  RAW: vmcnt(4) at u:p3-end leaves only u:{p2,p3} stages (tile u+2 slots)
//   outstanding -> all 4 slots of tile u+1 retired before its p0. The u+2 pair
//   retires at u+1:p3-end, read at u+2:p0. Prologue: 12 loads, vmcnt(4) retires
//   all of buf0. Tail: clamped stages keep issue uniform; leftover in-flight
//   loads target never-read slots.

__device__ __forceinline__ bf16x8 lds_frag(const short* slot, int r, int cbyte) {
  int byte = (r << 7) + cbyte;
  byte ^= (r & 7) << 4;
  return *reinterpret_cast<const bf16x8*>(reinterpret_cast<const char*>(slot) + byte);
}

__device__ __forceinline__ void stage_half(short* slot, const short* gbase, int ld,
                                           int isA, int h, int tid, int wave) {
#pragma unroll
  for (int j = 0; j < 2; ++j) {
    const int o = j * 8192 + tid * 16;              // linear LDS byte offset in slot
    const int r = o >> 7;                           // slot-local row
    const int cb = (o ^ ((r & 7) << 4)) & 127;      // pre-swizzled source col-byte
    const int g = isA ? (((r >> 6) << 7) + h * 64 + (r & 63))
                      : (((r >> 5) << 6) + h * 32 + (r & 31));
    __builtin_amdgcn_global_load_lds(
        (const __attribute__((address_space(1))) void*)(gbase + (size_t)g * ld + (cb >> 1)),
        (__attribute__((address_space(3))) void*)((char*)slot + j * 8192 + wave * 1024),
        16, 0, 0);
  }
}

template <typename S0, typename S1, typename S2, typename S3>
__device__ __forceinline__ void ktile16(short (*bufc)[8192], f32x4 (&acc)[2][2][4][2],
                                        int wr, int wc, int lane,
                                        S0 s0, S1 s1, S2 s2, S3 s3) {
  const int lr = lane & 15;
  const int ko = (lane >> 4) * 16;
  bf16x8 a0[2][4], a1[2][4], b0[2][2], b1[2][2];
  // ---- p0
  s0();
#pragma unroll
  for (int kk = 0; kk < 2; ++kk) {
#pragma unroll
    for (int m = 0; m < 4; ++m)
      a0[kk][m] = lds_frag(bufc[0], wr * 64 + m * 16 + lr, kk * 64 + ko);
#pragma unroll
    for (int n = 0; n < 2; ++n)
      b0[kk][n] = lds_frag(bufc[2], wc * 32 + n * 16 + lr, kk * 64 + ko);
  }
  __builtin_amdgcn_s_setprio(1);
#pragma unroll
  for (int kk = 0; kk < 2; ++kk)
#pragma unroll
    for (int m = 0; m < 4; ++m)
#pragma unroll
      for (int n = 0; n < 2; ++n)
        acc[0][0][m][n] = __builtin_amdgcn_mfma_f32_16x16x32_bf16(a0[kk][m], b0[kk][n],
                                                                  acc[0][0][m][n], 0, 0, 0);
  __builtin_amdgcn_s_setprio(0);
  // ---- p1
  s1();
#pragma unroll
  for (int kk = 0; kk < 2; ++kk)
#pragma unroll
    for (int n = 0; n < 2; ++n)
      b1[kk][n] = lds_frag(bufc[3], wc * 32 + n * 16 + lr, kk * 64 + ko);
  __builtin_amdgcn_s_setprio(1);
#pragma unroll
  for (int kk = 0; kk < 2; ++kk)
#pragma unroll
    for (int m = 0; m < 4; ++m)
#pragma unroll
      for (int n = 0; n < 2; ++n)
        acc[0][1][m][n] = __builtin_amdgcn_mfma_f32_16x16x32_bf16(a0[kk][m], b1[kk][n],
                                                                  acc[0][1][m][n], 0, 0, 0);
  __builtin_amdgcn_s_setprio(0);
  __builtin_amdgcn_s_barrier();          // bare barrier (p1-end)
  // ---- p2
  s2();
#pragma unroll
  for (int kk = 0; kk < 2; ++kk)
#pragma unroll
    for (int m = 0; m < 4; ++m)
      a1[kk][m] = lds_frag(bufc[1], wr * 64 + m * 16 + lr, kk * 64 + ko);
  __builtin_amdgcn_s_setprio(1);
#pragma unroll
  for (int kk = 0; kk < 2; ++kk)
#pragma unroll
    for (int m = 0; m < 4; ++m)
#pragma unroll
      for (int n = 0; n < 2; ++n)
        acc[1][0][m][n] = __builtin_amdgcn_mfma_f32_16x16x32_bf16(a1[kk][m], b0[kk][n],
                                                                  acc[1][0][m][n], 0, 0, 0);
  __builtin_amdgcn_s_setprio(0);
  // ---- p3
  s3();
  __builtin_amdgcn_s_setprio(1);
#pragma unroll
  for (int kk = 0; kk < 2; ++kk)
#pragma unroll
    for (int m = 0; m < 4; ++m)
#pragma unroll
      for (int n = 0; n < 2; ++n)
        acc[1][1][m][n] = __builtin_amdgcn_mfma_f32_16x16x32_bf16(a1[kk][m], b1[kk][n],
                                                                  acc[1][1][m][n], 0, 0, 0);
  __builtin_amdgcn_s_setprio(0);
  asm volatile("s_waitcnt vmcnt(4)" ::: "memory");
  __builtin_amdgcn_s_barrier();          // tile-end barrier
}

// ---------------- encode: feats[l] = relu(x[l] @ W_enc[l]^T) ----------------

__global__ __launch_bounds__(512, 2) void k_encode256(const short* __restrict__ xbf,
                                                      const short* __restrict__ webf,
                                                      float* __restrict__ feats_f32,
                                                      short* __restrict__ feats_bf) {
  __shared__ short lds[2][4][8192];
  const int l = blockIdx.z;
  const int row0 = blockIdx.y * 256;  // T
  const int col0 = blockIdx.x * 256;  // F
  const int tid = threadIdx.x;
  const int wave = tid >> 6, lane = tid & 63;
  const int wr = wave >> 2, wc = wave & 3;

  const short* A = xbf + (size_t)l * NT * NH + (size_t)row0 * NH;
  const short* B = webf + (size_t)l * NF * NH + (size_t)col0 * NH;

  f32x4 acc[2][2][4][2];
#pragma unroll
  for (int qa = 0; qa < 2; ++qa)
#pragma unroll
    for (int qb = 0; qb < 2; ++qb)
#pragma unroll
      for (int m = 0; m < 4; ++m)
#pragma unroll
        for (int n = 0; n < 2; ++n) {
          f32x4 z = {0.f, 0.f, 0.f, 0.f};
          acc[qa][qb][m][n] = z;
        }

  const int KT = NH / 64;  // 32
  stage_half(lds[0][0], A, NH, 1, 0, tid, wave);
  stage_half(lds[0][2], B, NH, 0, 0, tid, wave);
  stage_half(lds[0][1], A, NH, 1, 1, tid, wave);
  stage_half(lds[0][3], B, NH, 0, 1, tid, wave);
  stage_half(lds[1][0], A + 64, NH, 1, 0, tid, wave);
  stage_half(lds[1][2], B + 64, NH, 0, 0, tid, wave);
  asm volatile("s_waitcnt vmcnt(4)" ::: "memory");
  __builtin_amdgcn_s_barrier();

  for (int u = 0; u < KT; ++u) {
    short(*bufc)[8192] = lds[u & 1];
    short(*bufn)[8192] = lds[(u + 1) & 1];
    ktile16(bufc, acc, wr, wc, lane,
            [&] { stage_half(bufn[3], B + imin(u + 1, KT - 1) * 64, NH, 0, 1, tid, wave); },
            [&] { stage_half(bufn[1], A + imin(u + 1, KT - 1) * 64, NH, 1, 1, tid, wave); },
            [&] { stage_half(bufc[2], B + imin(u + 2, KT - 1) * 64, NH, 0, 0, tid, wave); },
            [&] { stage_half(bufc[0], A + imin(u + 2, KT - 1) * 64, NH, 1, 0, tid, wave); });
  }

  const int lr4 = (lane >> 4) * 4, lc = lane & 15;
  float* outF = feats_f32 + (size_t)l * NT * NF;
  short* outB = feats_bf + (size_t)l * NT * NF;
#pragma unroll
  for (int qa = 0; qa < 2; ++qa)
#pragma unroll
    for (int qb = 0; qb < 2; ++qb)
#pragma unroll
      for (int m = 0; m < 4; ++m)
#pragma unroll
        for (int n = 0; n < 2; ++n)
#pragma unroll
          for (int rg = 0; rg < 4; ++rg) {
            const int rr = row0 + wr * 128 + qa * 64 + m * 16 + lr4 + rg;
            const int cc = col0 + wc * 64 + qb * 32 + n * 16 + lc;
            float v = acc[qa][qb][m][n][rg];
            v = v > 0.f ? v : 0.f;
            outF[(size_t)rr * NF + cc] = v;
            outB[(size_t)rr * NF + cc] = f2bf(v);
          }
}

// ---------------- decode: recon[l] = sum_{s<=l} feats[s] @ W_dec[s,l]^T ----------------
// z-grid: l = 15 - z (heavy-first). Blocks sharing a W_dec panel (same x,z) sit
// 8 apart in dispatch order -> same XCD -> panel L2 reuse (verified property of
// this mapping; explicit remap in r8 measured nil, so keep the simple grid).

__global__ __launch_bounds__(512, 2) void k_decode256(const short* __restrict__ featsbf,
                                                      const short* __restrict__ wdbf,
                                                      float* __restrict__ recon) {
  __shared__ short lds[2][4][8192];
  const int l = (NL - 1) - blockIdx.z;
  const int row0 = blockIdx.y * 256;  // T
  const int col0 = blockIdx.x * 256;  // H
  const int tid = threadIdx.x;
  const int wave = tid >> 6, lane = tid & 63;
  const int wr = wave >> 2, wc = wave & 3;
  const int pbase = l * (l + 1) / 2;

  const short* Af = featsbf + (size_t)row0 * NF;
  const short* Bw = wdbf + (size_t)col0 * NF;

  f32x4 acc[2][2][4][2];
#pragma unroll
  for (int qa = 0; qa < 2; ++qa)
#pragma unroll
    for (int qb = 0; qb < 2; ++qb)
#pragma unroll
      for (int m = 0; m < 4; ++m)
#pragma unroll
        for (int n = 0; n < 2; ++n) {
          f32x4 z = {0.f, 0.f, 0.f, 0.f};
          acc[qa][qb][m][n] = z;
        }

  const int KT = 8 * (l + 1);
#define ABASE(kt) (Af + (size_t)((kt) >> 3) * (NT * NF) + ((kt)&7) * 64)
#define BBASE(kt) (Bw + (size_t)(pbase + ((kt) >> 3)) * (NH * NF) + ((kt)&7) * 64)

  stage_half(lds[0][0], ABASE(0), NF, 1, 0, tid, wave);
  stage_half(lds[0][2], BBASE(0), NF, 0, 0, tid, wave);
  stage_half(lds[0][1], ABASE(0), NF, 1, 1, tid, wave);
  stage_half(lds[0][3], BBASE(0), NF, 0, 1, tid, wave);
  stage_half(lds[1][0], ABASE(1), NF, 1, 0, tid, wave);
  stage_half(lds[1][2], BBASE(1), NF, 0, 0, tid, wave);
  asm volatile("s_waitcnt vmcnt(4)" ::: "memory");
  __builtin_amdgcn_s_barrier();

  for (int u = 0; u < KT; ++u) {
    short(*bufc)[8192] = lds[u & 1];
    short(*bufn)[8192] = lds[(u + 1) & 1];
    ktile16(bufc, acc, wr, wc, lane,
            [&] { stage_half(bufn[3], BBASE(imin(u + 1, KT - 1)), NF, 0, 1, tid, wave); },
            [&] { stage_half(bufn[1], ABASE(imin(u + 1, KT - 1)), NF, 1, 1, tid, wave); },
            [&] { stage_half(bufc[2], BBASE(imin(u + 2, KT - 1)), NF, 0, 0, tid, wave); },
            [&] { stage_half(bufc[0], ABASE(imin(u + 2, KT - 1)), NF, 1, 0, tid, wave); });
  }
#undef ABASE
#undef BBASE

  const int lr4 = (lane >> 4) * 4, lc = lane & 15;
  float* out = recon + (size_t)l * NT * NH;
#pragma unroll
  for (int qa = 0; qa < 2; ++qa)
#pragma unroll
    for (int qb = 0; qb < 2; ++qb)
#pragma unroll
      for (int m = 0; m < 4; ++m)
#pragma unroll
        for (int n = 0; n < 2; ++n)
#pragma unroll
          for (int rg = 0; rg < 4; ++rg) {
            const int rr = row0 + wr * 128 + qa * 64 + m * 16 + lr4 + rg;
            const int cc = col0 + wc * 64 + qb * 32 + n * 16 + lc;
            out[(size_t)rr * NH + cc] = acc[qa][qb][m][n][rg];
          }
}

// ---------------- launch ----------------

extern "C" void kernel_launch(void* const* d_in, const int* in_sizes, int n_in,
                              void* d_out, int out_size, void* d_ws, size_t ws_size,
                              hipStream_t stream) {
  const float* x = (const float*)d_in[0];
  const float* wenc = (const float*)d_in[1];
  const float* wdec = (const float*)d_in[2];

  float* feats_f32 = (float*)d_out;
  float* recon = feats_f32 + (size_t)NL * NT * NF;

  short* x_bf = (short*)d_ws;
  short* we_bf = x_bf + (size_t)NL * NT * NH;
  short* wd_bf = we_bf + (size_t)NL * NF * NH;
  short* ft_bf = wd_bf + (size_t)NPAIR * NH * NF;

  k_cvt_f32_bf16<<<2048, 256, 0, stream>>>(x, x_bf, NL * NT * NH / 4);
  k_cvt_f32_bf16<<<2048, 256, 0, stream>>>(wenc, we_bf, NL * NF * NH / 4);
  k_cvt_wdec<<<dim3(512, NPAIR), 256, 0, stream>>>(wdec, wd_bf);

  k_encode256<<<dim3(2, 8, 16), 512, 0, stream>>>(x_bf, we_bf, feats_f32, ft_bf);
  k_decode256<<<dim3(8, 8, 16), 512, 0, stream>>>(ft_bf, wd_bf, recon);
}

// Round 10
// 821.066 us; speedup vs baseline: 1.2113x; 1.0202x over previous
//
#include <hip/hip_runtime.h>

#define NL 16
#define NT 2048
#define NH 2048
#define NF 512
#define NPAIR 136

typedef short bf16x8 __attribute__((ext_vector_type(8)));
typedef float f32x4 __attribute__((ext_vector_type(4)));
typedef short s16x4 __attribute__((ext_vector_type(4)));

__device__ __forceinline__ short f2bf(float f) {
  union { float f; unsigned u; } x; x.f = f;
  unsigned r = (x.u + 0x7fffu + ((x.u >> 16) & 1u)) >> 16;
  return (short)r;
}

__device__ __forceinline__ int imin(int a, int b) { return a < b ? a : b; }

// ---------------- conversion kernels ----------------

__global__ void k_cvt_f32_bf16(const float* __restrict__ src, short* __restrict__ dst, int n4) {
  int i = blockIdx.x * blockDim.x + threadIdx.x;
  const int stride = gridDim.x * blockDim.x;
  for (; i < n4; i += stride) {
    const float4 v = reinterpret_cast<const float4*>(src)[i];
    s16x4 o;
    o[0] = f2bf(v.x); o[1] = f2bf(v.y); o[2] = f2bf(v.z); o[3] = f2bf(v.w);
    reinterpret_cast<s16x4*>(dst)[i] = o;
  }
}

__global__ void k_cvt_wdec(const float* __restrict__ wdec, short* __restrict__ dst) {
  const int p = blockIdx.y;
  int l = 0;
  while ((l + 1) * (l + 2) / 2 <= p) ++l;
  const int s = p - l * (l + 1) / 2;
  const float* src = wdec + (size_t)(s * NL + l) * (NH * NF);
  short* d = dst + (size_t)p * (NH * NF);
  const int n4 = NH * NF / 4;
  for (int i = blockIdx.x * blockDim.x + threadIdx.x; i < n4; i += gridDim.x * blockDim.x) {
    const float4 v = reinterpret_cast<const float4*>(src)[i];
    s16x4 o;
    o[0] = f2bf(v.x); o[1] = f2bf(v.y); o[2] = f2bf(v.z); o[3] = f2bf(v.w);
    reinterpret_cast<s16x4*>(d)[i] = o;
  }
}

// ---------------- 256x256 GEMM, flat K-tile (ONE barrier per tile) ----------------
// 8 waves: wr=wave>>2, wc=wave&3. Per-wave out 128x64, quadrants (qa,qb).
// LDS: lds[buf][slot][8192 shorts]; slot 0=A-half0, 1=A-half1, 2=B-half0, 3=B-half1.
//   A-half(h) local row r <-> tile row (r>>6)*128 + h*64 + (r&63)
//   B-half(h) local row r <-> tile row (r>>5)*64  + h*32 + (r&31)
// Swizzle: element (r, cbyte) at LDS byte ((r<<7)|cbyte) ^ ((r&7)<<4).
// K-tile u (single phase, frag-cached):
//   stage ALL of bufn = tile u+1 (8 gload_lds, issued first — max latency slack)
//   read b0,b1,a0 (16 frags); MFMA quadrants (0,0)+(0,1)
//   read a1 (8 frags);        MFMA quadrants (1,0)+(1,1)
//   s_waitcnt vmcnt(0) lgkmcnt(0); s_barrier
// Ledger: WAR trivial — stages always target the OTHER buffer; all reads of
//   bufc are lgkm-drained before the tile-end barrier, and the next tile's
//   stages into bufc are issued only after that barrier. RAW — the drain at
//   tile end retires tile u+1's stages before any wave crosses into u+1;
//   issue-to-deadline slack is the whole tile body (~2.5-3.5k cyc >> HBM 900).
//   Tail: stages simply skipped when u+1==KT (drain makes non-uniform safe).
// vs r5/r9 (4 sub-phases): removes the per-phase read-burst/MFMA-burst
// lockstep that idles the MFMA pipe 4x per tile with 1 block/CU.

__device__ __forceinline__ bf16x8 lds_frag(const short* slot, int r, int cbyte) {
  int byte = (r << 7) + cbyte;
  byte ^= (r & 7) << 4;
  return *reinterpret_cast<const bf16x8*>(reinterpret_cast<const char*>(slot) + byte);
}

__device__ __forceinline__ void stage_half(short* slot, const short* gbase, int ld,
                                           int isA, int h, int tid, int wave) {
#pragma unroll
  for (int j = 0; j < 2; ++j) {
    const int o = j * 8192 + tid * 16;              // linear LDS byte offset in slot
    const int r = o >> 7;                           // slot-local row
    const int cb = (o ^ ((r & 7) << 4)) & 127;      // pre-swizzled source col-byte
    const int g = isA ? (((r >> 6) << 7) + h * 64 + (r & 63))
                      : (((r >> 5) << 6) + h * 32 + (r & 31));
    __builtin_amdgcn_global_load_lds(
        (const __attribute__((address_space(1))) void*)(gbase + (size_t)g * ld + (cb >> 1)),
        (__attribute__((address_space(3))) void*)((char*)slot + j * 8192 + wave * 1024),
        16, 0, 0);
  }
}

__device__ __forceinline__ void stage_tile(short (*buf)[8192], const short* At,
                                           const short* Bt, int lda, int ldb,
                                           int tid, int wave) {
  stage_half(buf[0], At, lda, 1, 0, tid, wave);
  stage_half(buf[1], At, lda, 1, 1, tid, wave);
  stage_half(buf[2], Bt, ldb, 0, 0, tid, wave);
  stage_half(buf[3], Bt, ldb, 0, 1, tid, wave);
}

template <typename SFn>
__device__ __forceinline__ void ktile_flat(short (*bufc)[8192], f32x4 (&acc)[2][2][4][2],
                                           int wr, int wc, int lane, SFn stagefn) {
  const int lr = lane & 15;
  const int ko = (lane >> 4) * 16;
  stagefn();  // 8 global_load_lds into the OTHER buffer — issued first
  bf16x8 b0[2][2], b1[2][2], a0[2][4], a1[2][4];
#pragma unroll
  for (int kk = 0; kk < 2; ++kk) {
#pragma unroll
    for (int n = 0; n < 2; ++n) {
      b0[kk][n] = lds_frag(bufc[2], wc * 32 + n * 16 + lr, kk * 64 + ko);
      b1[kk][n] = lds_frag(bufc[3], wc * 32 + n * 16 + lr, kk * 64 + ko);
    }
#pragma unroll
    for (int m = 0; m < 4; ++m)
      a0[kk][m] = lds_frag(bufc[0], wr * 64 + m * 16 + lr, kk * 64 + ko);
  }
  __builtin_amdgcn_s_setprio(1);
#pragma unroll
  for (int kk = 0; kk < 2; ++kk)
#pragma unroll
    for (int m = 0; m < 4; ++m)
#pragma unroll
      for (int n = 0; n < 2; ++n) {
        acc[0][0][m][n] = __builtin_amdgcn_mfma_f32_16x16x32_bf16(a0[kk][m], b0[kk][n],
                                                                  acc[0][0][m][n], 0, 0, 0);
        acc[0][1][m][n] = __builtin_amdgcn_mfma_f32_16x16x32_bf16(a0[kk][m], b1[kk][n],
                                                                  acc[0][1][m][n], 0, 0, 0);
      }
  __builtin_amdgcn_s_setprio(0);
#pragma unroll
  for (int kk = 0; kk < 2; ++kk)
#pragma unroll
    for (int m = 0; m < 4; ++m)
      a1[kk][m] = lds_frag(bufc[1], wr * 64 + m * 16 + lr, kk * 64 + ko);
  __builtin_amdgcn_s_setprio(1);
#pragma unroll
  for (int kk = 0; kk < 2; ++kk)
#pragma unroll
    for (int m = 0; m < 4; ++m)
#pragma unroll
      for (int n = 0; n < 2; ++n) {
        acc[1][0][m][n] = __builtin_amdgcn_mfma_f32_16x16x32_bf16(a1[kk][m], b0[kk][n],
                                                                  acc[1][0][m][n], 0, 0, 0);
        acc[1][1][m][n] = __builtin_amdgcn_mfma_f32_16x16x32_bf16(a1[kk][m], b1[kk][n],
                                                                  acc[1][1][m][n], 0, 0, 0);
      }
  __builtin_amdgcn_s_setprio(0);
  asm volatile("s_waitcnt vmcnt(0) lgkmcnt(0)" ::: "memory");
  __builtin_amdgcn_s_barrier();
}

// ---------------- encode: feats[l] = relu(x[l] @ W_enc[l]^T) ----------------

__global__ __launch_bounds__(512, 2) void k_encode256(const short* __restrict__ xbf,
                                                      const short* __restrict__ webf,
                                                      float* __restrict__ feats_f32,
                                                      short* __restrict__ feats_bf) {
  __shared__ short lds[2][4][8192];
  const int l = blockIdx.z;
  const int row0 = blockIdx.y * 256;  // T
  const int col0 = blockIdx.x * 256;  // F
  const int tid = threadIdx.x;
  const int wave = tid >> 6, lane = tid & 63;
  const int wr = wave >> 2, wc = wave & 3;

  const short* A = xbf + (size_t)l * NT * NH + (size_t)row0 * NH;
  const short* B = webf + (size_t)l * NF * NH + (size_t)col0 * NH;

  f32x4 acc[2][2][4][2];
#pragma unroll
  for (int qa = 0; qa < 2; ++qa)
#pragma unroll
    for (int qb = 0; qb < 2; ++qb)
#pragma unroll
      for (int m = 0; m < 4; ++m)
#pragma unroll
        for (int n = 0; n < 2; ++n) {
          f32x4 z = {0.f, 0.f, 0.f, 0.f};
          acc[qa][qb][m][n] = z;
        }

  const int KT = NH / 64;  // 32
  stage_tile(lds[0], A, B, NH, NH, tid, wave);
  asm volatile("s_waitcnt vmcnt(0)" ::: "memory");
  __builtin_amdgcn_s_barrier();

  for (int u = 0; u < KT; ++u) {
    short(*bufc)[8192] = lds[u & 1];
    short(*bufn)[8192] = lds[(u + 1) & 1];
    ktile_flat(bufc, acc, wr, wc, lane, [&] {
      if (u + 1 < KT)
        stage_tile(bufn, A + (u + 1) * 64, B + (u + 1) * 64, NH, NH, tid, wave);
    });
  }

  const int lr4 = (lane >> 4) * 4, lc = lane & 15;
  float* outF = feats_f32 + (size_t)l * NT * NF;
  short* outB = feats_bf + (size_t)l * NT * NF;
#pragma unroll
  for (int qa = 0; qa < 2; ++qa)
#pragma unroll
    for (int qb = 0; qb < 2; ++qb)
#pragma unroll
      for (int m = 0; m < 4; ++m)
#pragma unroll
        for (int n = 0; n < 2; ++n)
#pragma unroll
          for (int rg = 0; rg < 4; ++rg) {
            const int rr = row0 + wr * 128 + qa * 64 + m * 16 + lr4 + rg;
            const int cc = col0 + wc * 64 + qb * 32 + n * 16 + lc;
            float v = acc[qa][qb][m][n][rg];
            v = v > 0.f ? v : 0.f;
            outF[(size_t)rr * NF + cc] = v;
            outB[(size_t)rr * NF + cc] = f2bf(v);
          }
}

// ---------------- decode: recon[l] = sum_{s<=l} feats[s] @ W_dec[s,l]^T ----------------
// z-grid: l = 15 - z (heavy-first). Blocks sharing a W_dec panel sit 8 apart
// in dispatch order -> same XCD -> panel L2 reuse.

__global__ __launch_bounds__(512, 2) void k_decode256(const short* __restrict__ featsbf,
                                                      const short* __restrict__ wdbf,
                                                      float* __restrict__ recon) {
  __shared__ short lds[2][4][8192];
  const int l = (NL - 1) - blockIdx.z;
  const int row0 = blockIdx.y * 256;  // T
  const int col0 = blockIdx.x * 256;  // H
  const int tid = threadIdx.x;
  const int wave = tid >> 6, lane = tid & 63;
  const int wr = wave >> 2, wc = wave & 3;
  const int pbase = l * (l + 1) / 2;

  const short* Af = featsbf + (size_t)row0 * NF;
  const short* Bw = wdbf + (size_t)col0 * NF;

  f32x4 acc[2][2][4][2];
#pragma unroll
  for (int qa = 0; qa < 2; ++qa)
#pragma unroll
    for (int qb = 0; qb < 2; ++qb)
#pragma unroll
      for (int m = 0; m < 4; ++m)
#pragma unroll
        for (int n = 0; n < 2; ++n) {
          f32x4 z = {0.f, 0.f, 0.f, 0.f};
          acc[qa][qb][m][n] = z;
        }

  const int KT = 8 * (l + 1);
#define ABASE(kt) (Af + (size_t)((kt) >> 3) * (NT * NF) + ((kt)&7) * 64)
#define BBASE(kt) (Bw + (size_t)(pbase + ((kt) >> 3)) * (NH * NF) + ((kt)&7) * 64)

  stage_tile(lds[0], ABASE(0), BBASE(0), NF, NF, tid, wave);
  asm volatile("s_waitcnt vmcnt(0)" ::: "memory");
  __builtin_amdgcn_s_barrier();

  for (int u = 0; u < KT; ++u) {
    short(*bufc)[8192] = lds[u & 1];
    short(*bufn)[8192] = lds[(u + 1) & 1];
    ktile_flat(bufc, acc, wr, wc, lane, [&] {
      if (u + 1 < KT)
        stage_tile(bufn, ABASE(u + 1), BBASE(u + 1), NF, NF, tid, wave);
    });
  }
#undef ABASE
#undef BBASE

  const int lr4 = (lane >> 4) * 4, lc = lane & 15;
  float* out = recon + (size_t)l * NT * NH;
#pragma unroll
  for (int qa = 0; qa < 2; ++qa)
#pragma unroll
    for (int qb = 0; qb < 2; ++qb)
#pragma unroll
      for (int m = 0; m < 4; ++m)
#pragma unroll
        for (int n = 0; n < 2; ++n)
#pragma unroll
          for (int rg = 0; rg < 4; ++rg) {
            const int rr = row0 + wr * 128 + qa * 64 + m * 16 + lr4 + rg;
            const int cc = col0 + wc * 64 + qb * 32 + n * 16 + lc;
            out[(size_t)rr * NH + cc] = acc[qa][qb][m][n][rg];
          }
}

// ---------------- launch ----------------

extern "C" void kernel_launch(void* const* d_in, const int* in_sizes, int n_in,
                              void* d_out, int out_size, void* d_ws, size_t ws_size,
                              hipStream_t stream) {
  const float* x = (const float*)d_in[0];
  const float* wenc = (const float*)d_in[1];
  const float* wdec = (const float*)d_in[2];

  float* feats_f32 = (float*)d_out;
  float* recon = feats_f32 + (size_t)NL * NT * NF;

  short* x_bf = (short*)d_ws;
  short* we_bf = x_bf + (size_t)NL * NT * NH;
  short* wd_bf = we_bf + (size_t)NL * NF * NH;
  short* ft_bf = wd_bf + (size_t)NPAIR * NH * NF;

  k_cvt_f32_bf16<<<2048, 256, 0, stream>>>(x, x_bf, NL * NT * NH / 4);
  k_cvt_f32_bf16<<<2048, 256, 0, stream>>>(wenc, we_bf, NL * NF * NH / 4);
  k_cvt_wdec<<<dim3(512, NPAIR), 256, 0, stream>>>(wdec, wd_bf);

  k_encode256<<<dim3(2, 8, 16), 512, 0, stream>>>(x_bf, we_bf, feats_f32, ft_bf);
  k_decode256<<<dim3(8, 8, 16), 512, 0, stream>>>(ft_bf, wd_bf, recon);
}